// Round 1
// baseline (216.645 us; speedup 1.0000x reference)
//
#include <hip/hip_runtime.h>

#define S_LEN 2048
#define BATCH 2
#define HDIM 1024
#define NH 16
#define DH 64
#define WINSZ 512
#define MROWS (BATCH * S_LEN)

typedef __attribute__((ext_vector_type(8))) short bfrag;
typedef __attribute__((ext_vector_type(4))) float f32x4;
typedef __attribute__((ext_vector_type(4))) int i128;

__device__ __forceinline__ short f2bf(float f) {
    union { float f; unsigned u; } v;
    v.f = f;
    unsigned r = v.u + 0x7fffu + ((v.u >> 16) & 1u);
    return (short)(r >> 16);
}

// ---------------- cast x (fp32 -> bf16), 4 elems/thread ----------------
__global__ void cast_bf_kernel(const float* __restrict__ in, short* __restrict__ out, int n4) {
    int i = blockIdx.x * blockDim.x + threadIdx.x;
    if (i < n4) {
        float4 v = ((const float4*)in)[i];
        union { short s[4]; int2 p; } u;
        u.s[0] = f2bf(v.x); u.s[1] = f2bf(v.y); u.s[2] = f2bf(v.z); u.s[3] = f2bf(v.w);
        ((int2*)out)[i] = u.p;
    }
}

// ---------------- transpose + cast: in (R x C fp32) -> out (C x R bf16) ----------------
__global__ void transpose_cast_kernel(const float* __restrict__ in, short* __restrict__ out,
                                      int R, int C) {
    __shared__ float tile[32][33];
    int tc0 = blockIdx.x * 32;
    int tr0 = blockIdx.y * 32;
    int t = threadIdx.x;
    int c = t & 31, r0 = t >> 5;
    #pragma unroll
    for (int k = 0; k < 4; ++k) {
        int r = r0 + k * 8;
        tile[r][c] = in[(size_t)(tr0 + r) * C + tc0 + c];
    }
    __syncthreads();
    int r2 = t & 31, c0 = t >> 5;
    #pragma unroll
    for (int k = 0; k < 4; ++k) {
        int c2 = c0 + k * 8;
        out[(size_t)(tc0 + c2) * R + tr0 + r2] = f2bf(tile[r2][c2]);
    }
}

// ---------------- GEMM: A (M x K bf16, row-major) @ Bt (N x K bf16, row-major) ----------------
// mode 0: QKV epilogue -> q[b][h][s][dh], k[b][h][s][dh], v^T[b][h][dh][s]  (bf16)
// mode 1: plain fp32 store to co (M x N)
__global__ __launch_bounds__(256, 2)
void gemm_bt(const short* __restrict__ A, const short* __restrict__ Bt,
             int M, int N, int K, int mode,
             short* __restrict__ qo, short* __restrict__ ko, short* __restrict__ vto,
             float* __restrict__ co)
{
    __shared__ __align__(16) short Al[128 * 32];
    __shared__ __align__(16) short Bl[128 * 32];
    const int t = threadIdx.x;
    const int lane = t & 63;
    const int wave = t >> 6;
    const int wr = wave >> 1, wc = wave & 1;
    const int m0 = blockIdx.y * 128, n0 = blockIdx.x * 128;
    const int lrow = lane & 15;
    const int lk8 = (lane >> 4) << 3;

    f32x4 acc[4][4];
    #pragma unroll
    for (int m = 0; m < 4; ++m)
        #pragma unroll
        for (int n = 0; n < 4; ++n)
            acc[m][n] = (f32x4){0.f, 0.f, 0.f, 0.f};

    for (int k0 = 0; k0 < K; k0 += 32) {
        #pragma unroll
        for (int c = 0; c < 2; ++c) {
            int ci = c * 256 + t;
            int row = ci >> 2;
            int col = (ci & 3) << 3;
            *(i128*)(&Al[row * 32 + col]) = *(const i128*)(&A[(size_t)(m0 + row) * K + k0 + col]);
            *(i128*)(&Bl[row * 32 + col]) = *(const i128*)(&Bt[(size_t)(n0 + row) * K + k0 + col]);
        }
        __syncthreads();
        bfrag af[4], bfr[4];
        #pragma unroll
        for (int m = 0; m < 4; ++m)
            af[m] = *(const bfrag*)(&Al[(wr * 64 + m * 16 + lrow) * 32 + lk8]);
        #pragma unroll
        for (int n = 0; n < 4; ++n)
            bfr[n] = *(const bfrag*)(&Bl[(wc * 64 + n * 16 + lrow) * 32 + lk8]);
        #pragma unroll
        for (int m = 0; m < 4; ++m)
            #pragma unroll
            for (int n = 0; n < 4; ++n)
                acc[m][n] = __builtin_amdgcn_mfma_f32_16x16x32_bf16(af[m], bfr[n], acc[m][n], 0, 0, 0);
        __syncthreads();
    }

    if (mode == 1) {
        #pragma unroll
        for (int m = 0; m < 4; ++m) {
            #pragma unroll
            for (int n = 0; n < 4; ++n) {
                int col = n0 + wc * 64 + n * 16 + lrow;
                int row0 = m0 + wr * 64 + m * 16 + ((lane >> 4) << 2);
                #pragma unroll
                for (int r = 0; r < 4; ++r)
                    co[(size_t)(row0 + r) * N + col] = acc[m][n][r];
            }
        }
    } else {
        #pragma unroll
        for (int m = 0; m < 4; ++m) {
            #pragma unroll
            for (int n = 0; n < 4; ++n) {
                int col = n0 + wc * 64 + n * 16 + lrow;   // 0..3071
                int which = col >> 10;
                int rem = col & 1023;
                int h = rem >> 6, dh = rem & 63;
                int row0 = m0 + wr * 64 + m * 16 + ((lane >> 4) << 2);
                #pragma unroll
                for (int r = 0; r < 4; ++r) {
                    int row = row0 + r;              // b*2048 + s
                    int b = row >> 11, s = row & 2047;
                    short val = f2bf(acc[m][n][r]);
                    if (which == 0)
                        qo[(((size_t)(b * NH + h)) * S_LEN + s) * DH + dh] = val;
                    else if (which == 1)
                        ko[(((size_t)(b * NH + h)) * S_LEN + s) * DH + dh] = val;
                    else
                        vto[(((size_t)(b * NH + h)) * DH + dh) * S_LEN + s] = val;
                }
            }
        }
    }
}

// ---------------- sliding-window flash attention ----------------
// 1 wave = 16 queries; block = 4 waves = 64 queries of one (b,h).
__global__ __launch_bounds__(256, 2)
void attn_kernel(const short* __restrict__ q_bf, const short* __restrict__ k_bf,
                 const short* __restrict__ vt, short* __restrict__ attno)
{
    __shared__ __align__(16) short Pl[4][16 * 32];
    const int blk = blockIdx.x;
    const int qblk = blk & (S_LEN / 64 - 1);
    const int bh = blk / (S_LEN / 64);
    const int wave = threadIdx.x >> 6, lane = threadIdx.x & 63;
    const int i0 = qblk * 64 + wave * 16;
    const short* qp = q_bf + (size_t)bh * S_LEN * DH;
    const short* kp = k_bf + (size_t)bh * S_LEN * DH;
    const short* vp = vt + (size_t)bh * DH * S_LEN;
    short* myP = &Pl[wave][0];

    const int lrow = lane & 15;
    const int lk8 = (lane >> 4) << 3;

    bfrag qf[2];
    qf[0] = *(const bfrag*)(&qp[(i0 + lrow) * DH + lk8]);
    qf[1] = *(const bfrag*)(&qp[(i0 + lrow) * DH + 32 + lk8]);

    f32x4 oacc[4];
    #pragma unroll
    for (int d = 0; d < 4; ++d) oacc[d] = (f32x4){0.f, 0.f, 0.f, 0.f};
    float mrun[4], lrun[4];
    #pragma unroll
    for (int r = 0; r < 4; ++r) { mrun[r] = -1e30f; lrun[r] = 0.f; }

    int j_lo = i0 - (WINSZ - 1);
    if (j_lo < 0) j_lo = 0;
    j_lo &= ~31;
    const int j_hi = i0 + 15;

    for (int j0 = j_lo; j0 <= j_hi; j0 += 32) {
        // ---- QK^T: scores 16q x 32keys (two 16x16 tiles) ----
        f32x4 sc[2];
        #pragma unroll
        for (int tc = 0; tc < 2; ++tc) {
            bfrag kf0 = *(const bfrag*)(&kp[(j0 + tc * 16 + lrow) * DH + lk8]);
            bfrag kf1 = *(const bfrag*)(&kp[(j0 + tc * 16 + lrow) * DH + 32 + lk8]);
            f32x4 z = (f32x4){0.f, 0.f, 0.f, 0.f};
            z = __builtin_amdgcn_mfma_f32_16x16x32_bf16(qf[0], kf0, z, 0, 0, 0);
            z = __builtin_amdgcn_mfma_f32_16x16x32_bf16(qf[1], kf1, z, 0, 0, 0);
            sc[tc] = z;
        }
        // ---- online softmax (rows spread over regs; row r held by 16 lanes) ----
        float rowscale[4];
        #pragma unroll
        for (int r = 0; r < 4; ++r) {
            int qi = i0 + ((lane >> 4) << 2) + r;
            int kj0 = j0 + lrow;
            int kj1 = j0 + 16 + lrow;
            float s0 = sc[0][r] * 0.125f;
            float s1 = sc[1][r] * 0.125f;
            s0 = ((kj0 <= qi) && (kj0 > qi - WINSZ)) ? s0 : -1e30f;
            s1 = ((kj1 <= qi) && (kj1 > qi - WINSZ)) ? s1 : -1e30f;
            float pm = fmaxf(s0, s1);
            #pragma unroll
            for (int off = 1; off < 16; off <<= 1) pm = fmaxf(pm, __shfl_xor(pm, off));
            float mnew = fmaxf(mrun[r], pm);
            float sc_r = __expf(mrun[r] - mnew);
            mrun[r] = mnew;
            float p0 = __expf(s0 - mnew);
            float p1 = __expf(s1 - mnew);
            float rs = p0 + p1;
            #pragma unroll
            for (int off = 1; off < 16; off <<= 1) rs += __shfl_xor(rs, off);
            lrun[r] = lrun[r] * sc_r + rs;
            rowscale[r] = sc_r;
            int prow = ((lane >> 4) << 2) + r;
            myP[prow * 32 + lrow] = f2bf(p0);
            myP[prow * 32 + 16 + lrow] = f2bf(p1);
        }
        #pragma unroll
        for (int d = 0; d < 4; ++d) {
            f32x4 o = oacc[d];
            o[0] *= rowscale[0]; o[1] *= rowscale[1];
            o[2] *= rowscale[2]; o[3] *= rowscale[3];
            oacc[d] = o;
        }
        asm volatile("s_waitcnt lgkmcnt(0)" ::: "memory");
        // ---- PV: P (16x32) @ V (32 x 64) ----
        bfrag pf = *(const bfrag*)(&myP[lrow * 32 + lk8]);
        #pragma unroll
        for (int d = 0; d < 4; ++d) {
            bfrag vf = *(const bfrag*)(&vp[(size_t)(d * 16 + lrow) * S_LEN + j0 + lk8]);
            oacc[d] = __builtin_amdgcn_mfma_f32_16x16x32_bf16(pf, vf, oacc[d], 0, 0, 0);
        }
    }

    // ---- epilogue: attno[b][s][h*64+dh] (bf16) ----
    const int b = bh >> 4, h = bh & 15;
    #pragma unroll
    for (int d = 0; d < 4; ++d) {
        #pragma unroll
        for (int r = 0; r < 4; ++r) {
            float val = oacc[d][r] / lrun[r];
            int qi = i0 + ((lane >> 4) << 2) + r;
            attno[((size_t)(b * S_LEN + qi)) * HDIM + h * DH + d * 16 + lrow] = f2bf(val);
        }
    }
}

extern "C" void kernel_launch(void* const* d_in, const int* in_sizes, int n_in,
                              void* d_out, int out_size, void* d_ws, size_t ws_size,
                              hipStream_t stream) {
    const float* x = (const float*)d_in[0];
    const float* Wqkv = (const float*)d_in[1];
    const float* Wout = (const float*)d_in[2];
    float* out = (float*)d_out;
    char* ws = (char*)d_ws;

    short* x_bf   = (short*)(ws);                    // 4096x1024        (8 MB)
    short* wqkv_t = (short*)(ws + 8388608);          // 3072x1024        (6 MB)
    short* wout_t = (short*)(ws + 14680064);         // 1024x1024        (2 MB)
    short* q_bf   = (short*)(ws + 16777216);         // [b][h][s][dh]    (8 MB)
    short* k_bf   = (short*)(ws + 25165824);         // [b][h][s][dh]    (8 MB)
    short* v_t    = (short*)(ws + 33554432);         // [b][h][dh][s]    (8 MB)
    short* attno  = (short*)(ws + 41943040);         // 4096x1024        (8 MB)

    cast_bf_kernel<<<4096, 256, 0, stream>>>(x, x_bf, MROWS * HDIM / 4);
    transpose_cast_kernel<<<dim3(96, 32), 256, 0, stream>>>(Wqkv, wqkv_t, 1024, 3072);
    transpose_cast_kernel<<<dim3(32, 32), 256, 0, stream>>>(Wout, wout_t, 1024, 1024);

    gemm_bt<<<dim3(24, 32), 256, 0, stream>>>(x_bf, wqkv_t, MROWS, 3 * HDIM, HDIM, 0,
                                              q_bf, k_bf, v_t, nullptr);
    attn_kernel<<<dim3(BATCH * NH * (S_LEN / 64)), 256, 0, stream>>>(q_bf, k_bf, v_t, attno);
    gemm_bt<<<dim3(8, 32), 256, 0, stream>>>(attno, wout_t, MROWS, HDIM, HDIM, 1,
                                             nullptr, nullptr, nullptr, out);
}

// Round 2
// 216.353 us; speedup vs baseline: 1.0013x; 1.0013x over previous
//
#include <hip/hip_runtime.h>

#define S_LEN 2048
#define BATCH 2
#define HDIM 1024
#define NH 16
#define DH 64
#define WINSZ 512
#define MROWS (BATCH * S_LEN)

typedef __attribute__((ext_vector_type(8))) short bfrag;
typedef __attribute__((ext_vector_type(4))) float f32x4;
typedef __attribute__((ext_vector_type(4))) int i128;

__device__ __forceinline__ short f2bf(float f) {
    union { float f; unsigned u; } v;
    v.f = f;
    unsigned r = v.u + 0x7fffu + ((v.u >> 16) & 1u);
    return (short)(r >> 16);
}

__device__ __forceinline__ void gload_lds16(const short* g, short* l) {
    __builtin_amdgcn_global_load_lds(
        (const __attribute__((address_space(1))) unsigned int*)g,
        (__attribute__((address_space(3))) unsigned int*)l, 16, 0, 0);
}

// ---------------- cast x (fp32 -> bf16), 4 elems/thread ----------------
__global__ void cast_bf_kernel(const float* __restrict__ in, short* __restrict__ out, int n4) {
    int i = blockIdx.x * blockDim.x + threadIdx.x;
    if (i < n4) {
        float4 v = ((const float4*)in)[i];
        union { short s[4]; int2 p; } u;
        u.s[0] = f2bf(v.x); u.s[1] = f2bf(v.y); u.s[2] = f2bf(v.z); u.s[3] = f2bf(v.w);
        ((int2*)out)[i] = u.p;
    }
}

// ---------------- transpose + cast: in (R x C fp32) -> out (C x R bf16) ----------------
__global__ void transpose_cast_kernel(const float* __restrict__ in, short* __restrict__ out,
                                      int R, int C) {
    __shared__ float tile[32][33];
    int tc0 = blockIdx.x * 32;
    int tr0 = blockIdx.y * 32;
    int t = threadIdx.x;
    int c = t & 31, r0 = t >> 5;
    #pragma unroll
    for (int k = 0; k < 4; ++k) {
        int r = r0 + k * 8;
        tile[r][c] = in[(size_t)(tr0 + r) * C + tc0 + c];
    }
    __syncthreads();
    int r2 = t & 31, c0 = t >> 5;
    #pragma unroll
    for (int k = 0; k < 4; ++k) {
        int c2 = c0 + k * 8;
        out[(size_t)(tc0 + c2) * R + tr0 + r2] = f2bf(tile[r2][c2]);
    }
}

// ---------------- GEMM: A (M x K bf16, row-major) @ Bt (N x K bf16, row-major) ----------------
// mode 0: QKV epilogue -> q[b][h][s][dh], k[b][h][s][dh], v^T[b][h][dh][s]  (bf16)
// mode 1: plain fp32 store to co (M x N)
__global__ __launch_bounds__(256, 2)
void gemm_bt(const short* __restrict__ A, const short* __restrict__ Bt,
             int M, int N, int K, int mode,
             short* __restrict__ qo, short* __restrict__ ko, short* __restrict__ vto,
             float* __restrict__ co)
{
    __shared__ __align__(16) short Al[128 * 32];
    __shared__ __align__(16) short Bl[128 * 32];
    const int t = threadIdx.x;
    const int lane = t & 63;
    const int wave = t >> 6;
    const int wr = wave >> 1, wc = wave & 1;
    const int m0 = blockIdx.y * 128, n0 = blockIdx.x * 128;
    const int lrow = lane & 15;
    const int lk8 = (lane >> 4) << 3;

    f32x4 acc[4][4];
    #pragma unroll
    for (int m = 0; m < 4; ++m)
        #pragma unroll
        for (int n = 0; n < 4; ++n)
            acc[m][n] = (f32x4){0.f, 0.f, 0.f, 0.f};

    // staging geometry: thread-chunk ci covers row=ci>>2, col=(ci&3)*8 -> LDS byte offset ci*16
    // (linear in lane => valid global_load_lds dest: uniform base + lane*16)
    const int ci0 = t;
    const int row0s = ci0 >> 2, col0s = (ci0 & 3) << 3;
    const int ci1 = 256 + t;
    const int row1s = ci1 >> 2, col1s = (ci1 & 3) << 3;
    short* AlB0 = &Al[(size_t)(wave * 64) * 8];
    short* BlB0 = &Bl[(size_t)(wave * 64) * 8];
    short* AlB1 = &Al[(size_t)(256 + wave * 64) * 8];
    short* BlB1 = &Bl[(size_t)(256 + wave * 64) * 8];

    for (int k0 = 0; k0 < K; k0 += 32) {
        gload_lds16(&A[(size_t)(m0 + row0s) * K + k0 + col0s], AlB0);
        gload_lds16(&Bt[(size_t)(n0 + row0s) * K + k0 + col0s], BlB0);
        gload_lds16(&A[(size_t)(m0 + row1s) * K + k0 + col1s], AlB1);
        gload_lds16(&Bt[(size_t)(n0 + row1s) * K + k0 + col1s], BlB1);
        __syncthreads();
        bfrag af[4], bfr[4];
        #pragma unroll
        for (int m = 0; m < 4; ++m)
            af[m] = *(const bfrag*)(&Al[(wr * 64 + m * 16 + lrow) * 32 + lk8]);
        #pragma unroll
        for (int n = 0; n < 4; ++n)
            bfr[n] = *(const bfrag*)(&Bl[(wc * 64 + n * 16 + lrow) * 32 + lk8]);
        #pragma unroll
        for (int m = 0; m < 4; ++m)
            #pragma unroll
            for (int n = 0; n < 4; ++n)
                acc[m][n] = __builtin_amdgcn_mfma_f32_16x16x32_bf16(af[m], bfr[n], acc[m][n], 0, 0, 0);
        __syncthreads();
    }

    if (mode == 1) {
        #pragma unroll
        for (int m = 0; m < 4; ++m) {
            #pragma unroll
            for (int n = 0; n < 4; ++n) {
                int col = n0 + wc * 64 + n * 16 + lrow;
                int row0 = m0 + wr * 64 + m * 16 + ((lane >> 4) << 2);
                #pragma unroll
                for (int r = 0; r < 4; ++r)
                    co[(size_t)(row0 + r) * N + col] = acc[m][n][r];
            }
        }
    } else {
        #pragma unroll
        for (int m = 0; m < 4; ++m) {
            #pragma unroll
            for (int n = 0; n < 4; ++n) {
                int col = n0 + wc * 64 + n * 16 + lrow;   // 0..3071
                int which = col >> 10;
                int rem = col & 1023;
                int h = rem >> 6, dh = rem & 63;
                int row0 = m0 + wr * 64 + m * 16 + ((lane >> 4) << 2);
                #pragma unroll
                for (int r = 0; r < 4; ++r) {
                    int row = row0 + r;              // b*2048 + s
                    int b = row >> 11, s = row & 2047;
                    short val = f2bf(acc[m][n][r]);
                    if (which == 0)
                        qo[(((size_t)(b * NH + h)) * S_LEN + s) * DH + dh] = val;
                    else if (which == 1)
                        ko[(((size_t)(b * NH + h)) * S_LEN + s) * DH + dh] = val;
                    else
                        vto[(((size_t)(b * NH + h)) * DH + dh) * S_LEN + s] = val;
                }
            }
        }
    }
}

// ---------------- sliding-window flash attention ----------------
// 1 wave = 16 queries, 64-key steps; block = 4 waves = 64 queries of one (b,h).
__global__ __launch_bounds__(256, 3)
void attn_kernel(const short* __restrict__ q_bf, const short* __restrict__ k_bf,
                 const short* __restrict__ vt, short* __restrict__ attno)
{
    __shared__ __align__(16) short Pl[4][16 * 64];
    const int blk = blockIdx.x;
    const int qblk = blk & (S_LEN / 64 - 1);
    const int bh = blk / (S_LEN / 64);
    const int wave = threadIdx.x >> 6, lane = threadIdx.x & 63;
    const int i0 = qblk * 64 + wave * 16;
    const short* qp = q_bf + (size_t)bh * S_LEN * DH;
    const short* kp = k_bf + (size_t)bh * S_LEN * DH;
    const short* vp = vt + (size_t)bh * DH * S_LEN;
    short* myP = &Pl[wave][0];

    const int lrow = lane & 15;
    const int lk8 = (lane >> 4) << 3;
    const int rbase = (lane >> 4) << 2;

    bfrag qf[2];
    qf[0] = *(const bfrag*)(&qp[(i0 + lrow) * DH + lk8]);
    qf[1] = *(const bfrag*)(&qp[(i0 + lrow) * DH + 32 + lk8]);

    f32x4 oacc[4];
    #pragma unroll
    for (int d = 0; d < 4; ++d) oacc[d] = (f32x4){0.f, 0.f, 0.f, 0.f};
    float mrun[4], lrun[4];
    #pragma unroll
    for (int r = 0; r < 4; ++r) { mrun[r] = -1e30f; lrun[r] = 0.f; }

    int j_lo = i0 - (WINSZ - 1);
    if (j_lo < 0) j_lo = 0;
    j_lo &= ~63;
    const int j_hi = i0 + 15;

    for (int j0 = j_lo; j0 <= j_hi; j0 += 64) {
        // ---- QK^T: scores 16q x 64keys (four 16x16 tiles, 8 independent MFMA) ----
        f32x4 sc[4];
        #pragma unroll
        for (int tc = 0; tc < 4; ++tc) {
            bfrag kf0 = *(const bfrag*)(&kp[(j0 + tc * 16 + lrow) * DH + lk8]);
            bfrag kf1 = *(const bfrag*)(&kp[(j0 + tc * 16 + lrow) * DH + 32 + lk8]);
            f32x4 z = (f32x4){0.f, 0.f, 0.f, 0.f};
            z = __builtin_amdgcn_mfma_f32_16x16x32_bf16(qf[0], kf0, z, 0, 0, 0);
            z = __builtin_amdgcn_mfma_f32_16x16x32_bf16(qf[1], kf1, z, 0, 0, 0);
            sc[tc] = z;
        }
        // interior steps need no masking (wave-uniform test)
        const bool nomask = (j0 >= i0 - (WINSZ - 16)) && (j0 + 63 <= i0);
        float rowscale[4];
        #pragma unroll
        for (int r = 0; r < 4; ++r) {
            int qi = i0 + rbase + r;
            float s[4];
            float pm = -1e30f;
            #pragma unroll
            for (int tc = 0; tc < 4; ++tc) {
                float sv = sc[tc][r] * 0.125f;
                if (!nomask) {
                    int kj = j0 + tc * 16 + lrow;
                    sv = ((kj <= qi) && (kj > qi - WINSZ)) ? sv : -1e30f;
                }
                s[tc] = sv;
                pm = fmaxf(pm, sv);
            }
            #pragma unroll
            for (int off = 1; off < 16; off <<= 1) pm = fmaxf(pm, __shfl_xor(pm, off));
            float mnew = fmaxf(mrun[r], pm);
            float sc_r = __expf(mrun[r] - mnew);
            mrun[r] = mnew;
            float rs = 0.f;
            float p[4];
            #pragma unroll
            for (int tc = 0; tc < 4; ++tc) { p[tc] = __expf(s[tc] - mnew); rs += p[tc]; }
            #pragma unroll
            for (int off = 1; off < 16; off <<= 1) rs += __shfl_xor(rs, off);
            lrun[r] = lrun[r] * sc_r + rs;
            rowscale[r] = sc_r;
            int prow = rbase + r;
            #pragma unroll
            for (int tc = 0; tc < 4; ++tc)
                myP[prow * 64 + tc * 16 + lrow] = f2bf(p[tc]);
        }
        #pragma unroll
        for (int d = 0; d < 4; ++d) {
            f32x4 o = oacc[d];
            o[0] *= rowscale[0]; o[1] *= rowscale[1];
            o[2] *= rowscale[2]; o[3] *= rowscale[3];
            oacc[d] = o;
        }
        asm volatile("s_waitcnt lgkmcnt(0)" ::: "memory");
        // ---- PV: P (16x64) @ V (64 x 64), two K=32 slices ----
        #pragma unroll
        for (int kt = 0; kt < 2; ++kt) {
            bfrag pf = *(const bfrag*)(&myP[lrow * 64 + kt * 32 + lk8]);
            #pragma unroll
            for (int d = 0; d < 4; ++d) {
                bfrag vf = *(const bfrag*)(&vp[(size_t)(d * 16 + lrow) * S_LEN + j0 + kt * 32 + lk8]);
                oacc[d] = __builtin_amdgcn_mfma_f32_16x16x32_bf16(pf, vf, oacc[d], 0, 0, 0);
            }
        }
    }

    // ---- epilogue: attno[b][s][h*64+dh] (bf16) ----
    const int b = bh >> 4, h = bh & 15;
    #pragma unroll
    for (int d = 0; d < 4; ++d) {
        #pragma unroll
        for (int r = 0; r < 4; ++r) {
            float val = oacc[d][r] / lrun[r];
            int qi = i0 + rbase + r;
            attno[((size_t)(b * S_LEN + qi)) * HDIM + h * DH + d * 16 + lrow] = f2bf(val);
        }
    }
}

extern "C" void kernel_launch(void* const* d_in, const int* in_sizes, int n_in,
                              void* d_out, int out_size, void* d_ws, size_t ws_size,
                              hipStream_t stream) {
    const float* x = (const float*)d_in[0];
    const float* Wqkv = (const float*)d_in[1];
    const float* Wout = (const float*)d_in[2];
    float* out = (float*)d_out;
    char* ws = (char*)d_ws;

    short* x_bf   = (short*)(ws);                    // 4096x1024        (8 MB)
    short* wqkv_t = (short*)(ws + 8388608);          // 3072x1024        (6 MB)
    short* wout_t = (short*)(ws + 14680064);         // 1024x1024        (2 MB)
    short* q_bf   = (short*)(ws + 16777216);         // [b][h][s][dh]    (8 MB)
    short* k_bf   = (short*)(ws + 25165824);         // [b][h][s][dh]    (8 MB)
    short* v_t    = (short*)(ws + 33554432);         // [b][h][dh][s]    (8 MB)
    short* attno  = (short*)(ws + 41943040);         // 4096x1024        (8 MB)

    cast_bf_kernel<<<4096, 256, 0, stream>>>(x, x_bf, MROWS * HDIM / 4);
    transpose_cast_kernel<<<dim3(96, 32), 256, 0, stream>>>(Wqkv, wqkv_t, 1024, 3072);
    transpose_cast_kernel<<<dim3(32, 32), 256, 0, stream>>>(Wout, wout_t, 1024, 1024);

    gemm_bt<<<dim3(24, 32), 256, 0, stream>>>(x_bf, wqkv_t, MROWS, 3 * HDIM, HDIM, 0,
                                              q_bf, k_bf, v_t, nullptr);
    attn_kernel<<<dim3(BATCH * NH * (S_LEN / 64)), 256, 0, stream>>>(q_bf, k_bf, v_t, attno);
    gemm_bt<<<dim3(8, 32), 256, 0, stream>>>(attno, wout_t, MROWS, HDIM, HDIM, 1,
                                             nullptr, nullptr, nullptr, out);
}

// Round 3
// 214.485 us; speedup vs baseline: 1.0101x; 1.0087x over previous
//
#include <hip/hip_runtime.h>

#define S_LEN 2048
#define BATCH 2
#define HDIM 1024
#define NH 16
#define DH 64
#define WINSZ 512
#define MROWS (BATCH * S_LEN)

typedef __attribute__((ext_vector_type(8))) short bfrag;
typedef __attribute__((ext_vector_type(4))) float f32x4;
typedef __attribute__((ext_vector_type(4))) int i128;

__device__ __forceinline__ short f2bf(float f) {
    union { float f; unsigned u; } v;
    v.f = f;
    unsigned r = v.u + 0x7fffu + ((v.u >> 16) & 1u);
    return (short)(r >> 16);
}

__device__ __forceinline__ void gload_lds16(const short* g, short* l) {
    __builtin_amdgcn_global_load_lds(
        (const __attribute__((address_space(1))) unsigned int*)g,
        (__attribute__((address_space(3))) unsigned int*)l, 16, 0, 0);
}

// ---------------- cast x (fp32 -> bf16), 4 elems/thread ----------------
__global__ void cast_bf_kernel(const float* __restrict__ in, short* __restrict__ out, int n4) {
    int i = blockIdx.x * blockDim.x + threadIdx.x;
    if (i < n4) {
        float4 v = ((const float4*)in)[i];
        union { short s[4]; int2 p; } u;
        u.s[0] = f2bf(v.x); u.s[1] = f2bf(v.y); u.s[2] = f2bf(v.z); u.s[3] = f2bf(v.w);
        ((int2*)out)[i] = u.p;
    }
}

// ---------------- transpose + cast: in (R x C fp32) -> out (C x R bf16) ----------------
__global__ void transpose_cast_kernel(const float* __restrict__ in, short* __restrict__ out,
                                      int R, int C) {
    __shared__ float tile[32][33];
    int tc0 = blockIdx.x * 32;
    int tr0 = blockIdx.y * 32;
    int t = threadIdx.x;
    int c = t & 31, r0 = t >> 5;
    #pragma unroll
    for (int k = 0; k < 4; ++k) {
        int r = r0 + k * 8;
        tile[r][c] = in[(size_t)(tr0 + r) * C + tc0 + c];
    }
    __syncthreads();
    int r2 = t & 31, c0 = t >> 5;
    #pragma unroll
    for (int k = 0; k < 4; ++k) {
        int c2 = c0 + k * 8;
        out[(size_t)(tc0 + c2) * R + tr0 + r2] = f2bf(tile[r2][c2]);
    }
}

// ---------------- GEMM: A (M x K bf16, row-major) @ Bt (N x K bf16, row-major) ----------------
// mode 0: QKV epilogue -> q[b][h][s][dh], k[b][h][s][dh], v^T[b][h][dh][s]  (bf16)
// mode 1: plain fp32 store to co (M x N)
__global__ __launch_bounds__(256, 2)
void gemm_bt(const short* __restrict__ A, const short* __restrict__ Bt,
             int M, int N, int K, int mode,
             short* __restrict__ qo, short* __restrict__ ko, short* __restrict__ vto,
             float* __restrict__ co)
{
    __shared__ __align__(16) short Al[128 * 32];
    __shared__ __align__(16) short Bl[128 * 32];
    const int t = threadIdx.x;
    const int lane = t & 63;
    const int wave = t >> 6;
    const int wr = wave >> 1, wc = wave & 1;
    const int m0 = blockIdx.y * 128, n0 = blockIdx.x * 128;
    const int lrow = lane & 15;
    const int lk8 = (lane >> 4) << 3;

    f32x4 acc[4][4];
    #pragma unroll
    for (int m = 0; m < 4; ++m)
        #pragma unroll
        for (int n = 0; n < 4; ++n)
            acc[m][n] = (f32x4){0.f, 0.f, 0.f, 0.f};

    const int ci0 = t;
    const int row0s = ci0 >> 2, col0s = (ci0 & 3) << 3;
    const int ci1 = 256 + t;
    const int row1s = ci1 >> 2, col1s = (ci1 & 3) << 3;
    short* AlB0 = &Al[(size_t)(wave * 64) * 8];
    short* BlB0 = &Bl[(size_t)(wave * 64) * 8];
    short* AlB1 = &Al[(size_t)(256 + wave * 64) * 8];
    short* BlB1 = &Bl[(size_t)(256 + wave * 64) * 8];

    for (int k0 = 0; k0 < K; k0 += 32) {
        gload_lds16(&A[(size_t)(m0 + row0s) * K + k0 + col0s], AlB0);
        gload_lds16(&Bt[(size_t)(n0 + row0s) * K + k0 + col0s], BlB0);
        gload_lds16(&A[(size_t)(m0 + row1s) * K + k0 + col1s], AlB1);
        gload_lds16(&Bt[(size_t)(n0 + row1s) * K + k0 + col1s], BlB1);
        __syncthreads();
        bfrag af[4], bfr[4];
        #pragma unroll
        for (int m = 0; m < 4; ++m)
            af[m] = *(const bfrag*)(&Al[(wr * 64 + m * 16 + lrow) * 32 + lk8]);
        #pragma unroll
        for (int n = 0; n < 4; ++n)
            bfr[n] = *(const bfrag*)(&Bl[(wc * 64 + n * 16 + lrow) * 32 + lk8]);
        #pragma unroll
        for (int m = 0; m < 4; ++m)
            #pragma unroll
            for (int n = 0; n < 4; ++n)
                acc[m][n] = __builtin_amdgcn_mfma_f32_16x16x32_bf16(af[m], bfr[n], acc[m][n], 0, 0, 0);
        __syncthreads();
    }

    if (mode == 1) {
        #pragma unroll
        for (int m = 0; m < 4; ++m) {
            #pragma unroll
            for (int n = 0; n < 4; ++n) {
                int col = n0 + wc * 64 + n * 16 + lrow;
                int row0 = m0 + wr * 64 + m * 16 + ((lane >> 4) << 2);
                #pragma unroll
                for (int r = 0; r < 4; ++r)
                    co[(size_t)(row0 + r) * N + col] = acc[m][n][r];
            }
        }
    } else {
        #pragma unroll
        for (int m = 0; m < 4; ++m) {
            #pragma unroll
            for (int n = 0; n < 4; ++n) {
                int col = n0 + wc * 64 + n * 16 + lrow;   // 0..3071
                int which = col >> 10;
                int rem = col & 1023;
                int h = rem >> 6, dh = rem & 63;
                int row0 = m0 + wr * 64 + m * 16 + ((lane >> 4) << 2);
                #pragma unroll
                for (int r = 0; r < 4; ++r) {
                    int row = row0 + r;              // b*2048 + s
                    int b = row >> 11, s = row & 2047;
                    short val = f2bf(acc[m][n][r]);
                    if (which == 0)
                        qo[(((size_t)(b * NH + h)) * S_LEN + s) * DH + dh] = val;
                    else if (which == 1)
                        ko[(((size_t)(b * NH + h)) * S_LEN + s) * DH + dh] = val;
                    else
                        vto[(((size_t)(b * NH + h)) * DH + dh) * S_LEN + s] = val;
                }
            }
        }
    }
}

// ---------------- sliding-window flash attention (swapped-operand MFMA) ----------------
// 1 wave = 16 queries, 64-key steps; block = 4 waves = 64 queries of one (b,h).
// QK^T computed as mfma(K,Q): lane holds scores for q = lane&15, keys 4g+reg per tile.
// PV computed as mfma(V^T,P): O[d][q=lane&15] -> m/l/rescale are per-lane scalars.
__global__ __launch_bounds__(256, 3)
void attn_kernel(const short* __restrict__ q_bf, const short* __restrict__ k_bf,
                 const short* __restrict__ vt, short* __restrict__ attno)
{
    __shared__ __align__(16) short Pl[4][16 * 64];
    const int blk = blockIdx.x;
    const int qblk = blk & (S_LEN / 64 - 1);
    const int bh = blk / (S_LEN / 64);
    const int wave = threadIdx.x >> 6, lane = threadIdx.x & 63;
    const int i0 = qblk * 64 + wave * 16;
    const short* qp = q_bf + (size_t)bh * S_LEN * DH;
    const short* kp = k_bf + (size_t)bh * S_LEN * DH;
    const short* vp = vt + (size_t)bh * DH * S_LEN;
    char* myP = (char*)&Pl[wave][0];

    const int lq = lane & 15;          // this lane's query (local)
    const int g = lane >> 4;           // lane group 0..3
    const int lk8 = g << 3;
    const int swz = (lq & 7) << 4;     // LDS XOR swizzle (bits 4-6, keeps 16B align)

    bfrag qf[2];
    qf[0] = *(const bfrag*)(&qp[(i0 + lq) * DH + lk8]);
    qf[1] = *(const bfrag*)(&qp[(i0 + lq) * DH + 32 + lk8]);

    f32x4 oacc[4];
    #pragma unroll
    for (int d = 0; d < 4; ++d) oacc[d] = (f32x4){0.f, 0.f, 0.f, 0.f};
    float m2 = -1e30f, lrun = 0.f;     // log2-domain running max, denom
    const float QSCALE = 0.125f * 1.44269504f;   // 1/sqrt(64) * log2(e)
    const int qi = i0 + lq;

    int j_lo = i0 - (WINSZ - 1);
    if (j_lo < 0) j_lo = 0;
    j_lo &= ~63;
    const int j_hi = i0 + 15;

    for (int j0 = j_lo; j0 <= j_hi; j0 += 64) {
        // ---- K fragments for 4 key-tiles ----
        bfrag kf0[4], kf1[4];
        #pragma unroll
        for (int tc = 0; tc < 4; ++tc) {
            kf0[tc] = *(const bfrag*)(&kp[(j0 + tc * 16 + lq) * DH + lk8]);
            kf1[tc] = *(const bfrag*)(&kp[(j0 + tc * 16 + lq) * DH + 32 + lk8]);
        }
        // ---- QK^T swapped: sc[tc][r] = score(key=j0+tc*16+4g+r, q=qi) ----
        f32x4 sc[4];
        #pragma unroll
        for (int tc = 0; tc < 4; ++tc) {
            f32x4 z = (f32x4){0.f, 0.f, 0.f, 0.f};
            z = __builtin_amdgcn_mfma_f32_16x16x32_bf16(kf0[tc], qf[0], z, 0, 0, 0);
            z = __builtin_amdgcn_mfma_f32_16x16x32_bf16(kf1[tc], qf[1], z, 0, 0, 0);
            sc[tc] = z;
        }
        // ---- V fragments issued now; latency hides under softmax ----
        bfrag vf[2][4];
        #pragma unroll
        for (int kt = 0; kt < 2; ++kt)
            #pragma unroll
            for (int d = 0; d < 4; ++d)
                vf[kt][d] = *(const bfrag*)(&vp[(size_t)(d * 16 + lq) * S_LEN + j0 + kt * 32 + lk8]);

        // ---- softmax: reduction axis is in-lane + 2 shuffles ----
        const bool nomask = (j0 >= i0 - (WINSZ - 16)) && (j0 + 63 <= i0);
        float s[4][4];
        float pm = -1e30f;
        #pragma unroll
        for (int tc = 0; tc < 4; ++tc) {
            #pragma unroll
            for (int r = 0; r < 4; ++r) {
                float sv = sc[tc][r] * QSCALE;
                if (!nomask) {
                    int kj = j0 + tc * 16 + 4 * g + r;
                    sv = ((kj <= qi) && (kj > qi - WINSZ)) ? sv : -1e30f;
                }
                s[tc][r] = sv;
                pm = fmaxf(pm, sv);
            }
        }
        pm = fmaxf(pm, __shfl_xor(pm, 16));
        pm = fmaxf(pm, __shfl_xor(pm, 32));
        float mnew = fmaxf(m2, pm);
        float scale_old = exp2f(m2 - mnew);
        m2 = mnew;
        float p[4][4];
        float rs = 0.f;
        #pragma unroll
        for (int tc = 0; tc < 4; ++tc)
            #pragma unroll
            for (int r = 0; r < 4; ++r) {
                p[tc][r] = exp2f(s[tc][r] - mnew);
                rs += p[tc][r];
            }
        rs += __shfl_xor(rs, 16);
        rs += __shfl_xor(rs, 32);
        lrun = lrun * scale_old + rs;
        // ---- rescale O (per-lane scalar) ----
        #pragma unroll
        for (int d = 0; d < 4; ++d) {
            f32x4 o = oacc[d];
            o[0] *= scale_old; o[1] *= scale_old; o[2] *= scale_old; o[3] *= scale_old;
            oacc[d] = o;
        }
        // ---- P -> LDS (bf16, XOR-swizzled): lane writes P[q=lq][k=tc*16+4g+0..3] ----
        #pragma unroll
        for (int tc = 0; tc < 4; ++tc) {
            union { short sh[4]; int2 w; } u;
            u.sh[0] = f2bf(p[tc][0]); u.sh[1] = f2bf(p[tc][1]);
            u.sh[2] = f2bf(p[tc][2]); u.sh[3] = f2bf(p[tc][3]);
            int wb = (lq * 128 + tc * 32 + g * 8) ^ swz;
            *(int2*)(myP + wb) = u.w;
        }
        asm volatile("s_waitcnt lgkmcnt(0)" ::: "memory");
        // ---- PV swapped: oacc[d] += mfma(V^T_frag, P_frag) ----
        #pragma unroll
        for (int kt = 0; kt < 2; ++kt) {
            int rb = (lq * 128 + kt * 64 + g * 16) ^ swz;
            bfrag pf = *(const bfrag*)(myP + rb);
            #pragma unroll
            for (int d = 0; d < 4; ++d)
                oacc[d] = __builtin_amdgcn_mfma_f32_16x16x32_bf16(vf[kt][d], pf, oacc[d], 0, 0, 0);
        }
    }

    // ---- epilogue: O[d][q=lq] / lrun -> attno[b][s=qi][h*64 + d] ----
    const int b = bh >> 4, h = bh & 15;
    const float inv_l = 1.f / lrun;
    size_t rowbase = ((size_t)(b * S_LEN + qi)) * HDIM + h * DH;
    #pragma unroll
    for (int d = 0; d < 4; ++d) {
        union { short sh[4]; int2 w; } u;
        #pragma unroll
        for (int r = 0; r < 4; ++r)
            u.sh[r] = f2bf(oacc[d][r] * inv_l);
        *(int2*)(&attno[rowbase + d * 16 + 4 * g]) = u.w;
    }
}

extern "C" void kernel_launch(void* const* d_in, const int* in_sizes, int n_in,
                              void* d_out, int out_size, void* d_ws, size_t ws_size,
                              hipStream_t stream) {
    const float* x = (const float*)d_in[0];
    const float* Wqkv = (const float*)d_in[1];
    const float* Wout = (const float*)d_in[2];
    float* out = (float*)d_out;
    char* ws = (char*)d_ws;

    short* x_bf   = (short*)(ws);                    // 4096x1024        (8 MB)
    short* wqkv_t = (short*)(ws + 8388608);          // 3072x1024        (6 MB)
    short* wout_t = (short*)(ws + 14680064);         // 1024x1024        (2 MB)
    short* q_bf   = (short*)(ws + 16777216);         // [b][h][s][dh]    (8 MB)
    short* k_bf   = (short*)(ws + 25165824);         // [b][h][s][dh]    (8 MB)
    short* v_t    = (short*)(ws + 33554432);         // [b][h][dh][s]    (8 MB)
    short* attno  = (short*)(ws + 41943040);         // 4096x1024        (8 MB)

    cast_bf_kernel<<<4096, 256, 0, stream>>>(x, x_bf, MROWS * HDIM / 4);
    transpose_cast_kernel<<<dim3(96, 32), 256, 0, stream>>>(Wqkv, wqkv_t, 1024, 3072);
    transpose_cast_kernel<<<dim3(32, 32), 256, 0, stream>>>(Wout, wout_t, 1024, 1024);

    gemm_bt<<<dim3(24, 32), 256, 0, stream>>>(x_bf, wqkv_t, MROWS, 3 * HDIM, HDIM, 0,
                                              q_bf, k_bf, v_t, nullptr);
    attn_kernel<<<dim3(BATCH * NH * (S_LEN / 64)), 256, 0, stream>>>(q_bf, k_bf, v_t, attno);
    gemm_bt<<<dim3(8, 32), 256, 0, stream>>>(attno, wout_t, MROWS, HDIM, HDIM, 1,
                                             nullptr, nullptr, nullptr, out);
}

// Round 4
// 175.899 us; speedup vs baseline: 1.2316x; 1.2194x over previous
//
#include <hip/hip_runtime.h>

#define S_LEN 2048
#define BATCH 2
#define HDIM 1024
#define NH 16
#define DH 64
#define WINSZ 512
#define MROWS (BATCH * S_LEN)

typedef __attribute__((ext_vector_type(8))) short bfrag;
typedef __attribute__((ext_vector_type(4))) float f32x4;
typedef __attribute__((ext_vector_type(4))) int i128;

__device__ __forceinline__ short f2bf(float f) {
    union { float f; unsigned u; } v;
    v.f = f;
    unsigned r = v.u + 0x7fffu + ((v.u >> 16) & 1u);
    return (short)(r >> 16);
}

__device__ __forceinline__ void gload_lds16(const short* g, short* l) {
    __builtin_amdgcn_global_load_lds(
        (const __attribute__((address_space(1))) unsigned int*)g,
        (__attribute__((address_space(3))) unsigned int*)l, 16, 0, 0);
}

// ---------------- cast x (fp32 -> bf16), 4 elems/thread ----------------
__global__ void cast_bf_kernel(const float* __restrict__ in, short* __restrict__ out, int n4) {
    int i = blockIdx.x * blockDim.x + threadIdx.x;
    if (i < n4) {
        float4 v = ((const float4*)in)[i];
        union { short s[4]; int2 p; } u;
        u.s[0] = f2bf(v.x); u.s[1] = f2bf(v.y); u.s[2] = f2bf(v.z); u.s[3] = f2bf(v.w);
        ((int2*)out)[i] = u.p;
    }
}

// ---------------- transpose + cast: in (R x C fp32) -> out (C x R bf16) ----------------
__global__ void transpose_cast_kernel(const float* __restrict__ in, short* __restrict__ out,
                                      int R, int C) {
    __shared__ float tile[32][33];
    int tc0 = blockIdx.x * 32;
    int tr0 = blockIdx.y * 32;
    int t = threadIdx.x;
    int c = t & 31, r0 = t >> 5;
    #pragma unroll
    for (int k = 0; k < 4; ++k) {
        int r = r0 + k * 8;
        tile[r][c] = in[(size_t)(tr0 + r) * C + tc0 + c];
    }
    __syncthreads();
    int r2 = t & 31, c0 = t >> 5;
    #pragma unroll
    for (int k = 0; k < 4; ++k) {
        int c2 = c0 + k * 8;
        out[(size_t)(tc0 + c2) * R + tr0 + r2] = f2bf(tile[r2][c2]);
    }
}

// ---------------- GEMM: A (M x K bf16, row-major) @ Bt (N x K bf16, row-major) ----------------
__global__ __launch_bounds__(256, 2)
void gemm_bt(const short* __restrict__ A, const short* __restrict__ Bt,
             int M, int N, int K, int mode,
             short* __restrict__ qo, short* __restrict__ ko, short* __restrict__ vto,
             float* __restrict__ co)
{
    __shared__ __align__(16) short Al[128 * 32];
    __shared__ __align__(16) short Bl[128 * 32];
    const int t = threadIdx.x;
    const int lane = t & 63;
    const int wave = t >> 6;
    const int wr = wave >> 1, wc = wave & 1;
    const int m0 = blockIdx.y * 128, n0 = blockIdx.x * 128;
    const int lrow = lane & 15;
    const int lk8 = (lane >> 4) << 3;

    f32x4 acc[4][4];
    #pragma unroll
    for (int m = 0; m < 4; ++m)
        #pragma unroll
        for (int n = 0; n < 4; ++n)
            acc[m][n] = (f32x4){0.f, 0.f, 0.f, 0.f};

    const int ci0 = t;
    const int row0s = ci0 >> 2, col0s = (ci0 & 3) << 3;
    const int ci1 = 256 + t;
    const int row1s = ci1 >> 2, col1s = (ci1 & 3) << 3;
    short* AlB0 = &Al[(size_t)(wave * 64) * 8];
    short* BlB0 = &Bl[(size_t)(wave * 64) * 8];
    short* AlB1 = &Al[(size_t)(256 + wave * 64) * 8];
    short* BlB1 = &Bl[(size_t)(256 + wave * 64) * 8];

    for (int k0 = 0; k0 < K; k0 += 32) {
        gload_lds16(&A[(size_t)(m0 + row0s) * K + k0 + col0s], AlB0);
        gload_lds16(&Bt[(size_t)(n0 + row0s) * K + k0 + col0s], BlB0);
        gload_lds16(&A[(size_t)(m0 + row1s) * K + k0 + col1s], AlB1);
        gload_lds16(&Bt[(size_t)(n0 + row1s) * K + k0 + col1s], BlB1);
        __syncthreads();
        bfrag af[4], bfr[4];
        #pragma unroll
        for (int m = 0; m < 4; ++m)
            af[m] = *(const bfrag*)(&Al[(wr * 64 + m * 16 + lrow) * 32 + lk8]);
        #pragma unroll
        for (int n = 0; n < 4; ++n)
            bfr[n] = *(const bfrag*)(&Bl[(wc * 64 + n * 16 + lrow) * 32 + lk8]);
        #pragma unroll
        for (int m = 0; m < 4; ++m)
            #pragma unroll
            for (int n = 0; n < 4; ++n)
                acc[m][n] = __builtin_amdgcn_mfma_f32_16x16x32_bf16(af[m], bfr[n], acc[m][n], 0, 0, 0);
        __syncthreads();
    }

    if (mode == 1) {
        #pragma unroll
        for (int m = 0; m < 4; ++m) {
            #pragma unroll
            for (int n = 0; n < 4; ++n) {
                int col = n0 + wc * 64 + n * 16 + lrow;
                int row0 = m0 + wr * 64 + m * 16 + ((lane >> 4) << 2);
                #pragma unroll
                for (int r = 0; r < 4; ++r)
                    co[(size_t)(row0 + r) * N + col] = acc[m][n][r];
            }
        }
    } else {
        #pragma unroll
        for (int m = 0; m < 4; ++m) {
            #pragma unroll
            for (int n = 0; n < 4; ++n) {
                int col = n0 + wc * 64 + n * 16 + lrow;   // 0..3071
                int which = col >> 10;
                int rem = col & 1023;
                int h = rem >> 6, dh = rem & 63;
                int row0 = m0 + wr * 64 + m * 16 + ((lane >> 4) << 2);
                #pragma unroll
                for (int r = 0; r < 4; ++r) {
                    int row = row0 + r;              // b*2048 + s
                    int b = row >> 11, s = row & 2047;
                    short val = f2bf(acc[m][n][r]);
                    if (which == 0)
                        qo[(((size_t)(b * NH + h)) * S_LEN + s) * DH + dh] = val;
                    else if (which == 1)
                        ko[(((size_t)(b * NH + h)) * S_LEN + s) * DH + dh] = val;
                    else
                        vto[(((size_t)(b * NH + h)) * DH + dh) * S_LEN + s] = val;
                }
            }
        }
    }
}

// ---------------- sliding-window flash attention (block-shared LDS K/V tiles) ----------------
// Block = 64 queries of one (b,h); 4 waves of 16 queries. 64-key tiles staged to LDS
// cooperatively (double-buffered, global_load_lds w=16, chunk-XOR pre-swizzled source).
// Swapped-operand MFMA: lane owns q=lane&15; softmax per-lane + 2 shuffles.
__global__ __launch_bounds__(256, 4)
void attn_kernel(const short* __restrict__ q_bf, const short* __restrict__ k_bf,
                 const short* __restrict__ vt, short* __restrict__ attno)
{
    __shared__ __align__(16) short Kl[2][64 * 64];
    __shared__ __align__(16) short Vl[2][64 * 64];
    __shared__ __align__(16) short Pl[4][16 * 64];

    // XCD-grouping swizzle: each XCD owns 4 consecutive bh (1024 blocks, %8==0 -> bijective)
    const int bid = blockIdx.x;
    const int logical = (bid & 7) * 128 + (bid >> 3);
    const int qblk = logical & 31;
    const int bh = logical >> 5;

    const int t = threadIdx.x;
    const int wave = t >> 6, lane = t & 63;
    const int qb0 = qblk * 64;
    const int i0 = qb0 + wave * 16;
    const short* qp = q_bf + (size_t)bh * S_LEN * DH;
    const short* kp = k_bf + (size_t)bh * S_LEN * DH;
    const short* vp = vt + (size_t)bh * DH * S_LEN;
    char* myP = (char*)&Pl[wave][0];

    const int lq = lane & 15;          // this lane's query (local)
    const int g = lane >> 4;           // lane group 0..3
    const int swz = (lq & 7) << 4;     // P-LDS XOR swizzle
    const int l7 = lq & 7;             // K/V tile column swizzle key

    bfrag qf[2];
    qf[0] = *(const bfrag*)(&qp[(i0 + lq) * DH + (g << 3)]);
    qf[1] = *(const bfrag*)(&qp[(i0 + lq) * DH + 32 + (g << 3)]);

    f32x4 oacc[4];
    #pragma unroll
    for (int d = 0; d < 4; ++d) oacc[d] = (f32x4){0.f, 0.f, 0.f, 0.f};
    float m2 = -1e30f, lrun = 0.f;
    const float QSCALE = 0.125f * 1.44269504f;   // 1/sqrt(64) * log2(e)
    const int qi = i0 + lq;

    int j_lo = qb0 - (WINSZ - 1);
    if (j_lo < 0) j_lo = 0;
    j_lo &= ~63;
    const int nT = ((qb0 + 64) - j_lo) >> 6;     // 1..9 tiles, uniform across waves

    // stage tile at j0 into (kbuf, vbuf): LDS linear dest, source chunk-XOR swizzled
    auto stage = [&](int j0, short* kbuf, short* vbuf) {
        #pragma unroll
        for (int qq = 0; qq < 2; ++qq) {
            int chunk = qq * 256 + wave * 64 + lane;
            int row = chunk >> 3;
            int cc = (chunk & 7) ^ (row & 7);
            short* kdst = kbuf + (size_t)(qq * 256 + wave * 64) * 8;
            short* vdst = vbuf + (size_t)(qq * 256 + wave * 64) * 8;
            gload_lds16(kp + (size_t)(j_lo + j0 + row) * DH + cc * 8, kdst);
            gload_lds16(vp + (size_t)row * S_LEN + j_lo + j0 + cc * 8, vdst);
        }
    };

    stage(0, Kl[0], Vl[0]);
    __syncthreads();

    for (int ti = 0; ti < nT; ++ti) {
        const int cur = ti & 1;
        const int j0 = j_lo + ti * 64;
        if (ti + 1 < nT) stage((ti + 1) * 64, Kl[cur ^ 1], Vl[cur ^ 1]);

        const short* Kc = Kl[cur];
        const short* Vc = Vl[cur];

        // ---- QK^T swapped: sc[tc][r] = score(key=j0+tc*16+4g+r, q=qi) ----
        f32x4 sc[4];
        #pragma unroll
        for (int tc = 0; tc < 4; ++tc) {
            bfrag a0 = *(const bfrag*)(&Kc[(tc * 16 + lq) * 64 + ((g ^ l7) << 3)]);
            bfrag a1 = *(const bfrag*)(&Kc[(tc * 16 + lq) * 64 + (((4 | g) ^ l7) << 3)]);
            f32x4 z = (f32x4){0.f, 0.f, 0.f, 0.f};
            z = __builtin_amdgcn_mfma_f32_16x16x32_bf16(a0, qf[0], z, 0, 0, 0);
            z = __builtin_amdgcn_mfma_f32_16x16x32_bf16(a1, qf[1], z, 0, 0, 0);
            sc[tc] = z;
        }

        // ---- softmax: reduction axis in-lane + 2 shuffles ----
        const bool nomask = (j0 >= i0 - (WINSZ - 16)) && (j0 + 63 <= i0);
        float s[4][4];
        float pm = -1e30f;
        #pragma unroll
        for (int tc = 0; tc < 4; ++tc) {
            #pragma unroll
            for (int r = 0; r < 4; ++r) {
                float sv = sc[tc][r] * QSCALE;
                if (!nomask) {
                    int kj = j0 + tc * 16 + 4 * g + r;
                    sv = ((kj <= qi) && (kj > qi - WINSZ)) ? sv : -1e30f;
                }
                s[tc][r] = sv;
                pm = fmaxf(pm, sv);
            }
        }
        pm = fmaxf(pm, __shfl_xor(pm, 16));
        pm = fmaxf(pm, __shfl_xor(pm, 32));
        float mnew = fmaxf(m2, pm);
        float scale_old = exp2f(m2 - mnew);
        m2 = mnew;
        float p[4][4];
        float rs = 0.f;
        #pragma unroll
        for (int tc = 0; tc < 4; ++tc)
            #pragma unroll
            for (int r = 0; r < 4; ++r) {
                p[tc][r] = exp2f(s[tc][r] - mnew);
                rs += p[tc][r];
            }
        rs += __shfl_xor(rs, 16);
        rs += __shfl_xor(rs, 32);
        lrun = lrun * scale_old + rs;
        #pragma unroll
        for (int d = 0; d < 4; ++d) {
            f32x4 o = oacc[d];
            o[0] *= scale_old; o[1] *= scale_old; o[2] *= scale_old; o[3] *= scale_old;
            oacc[d] = o;
        }

        // ---- P -> LDS (bf16, XOR-swizzled) ----
        #pragma unroll
        for (int tc = 0; tc < 4; ++tc) {
            union { short sh[4]; int2 w; } u;
            u.sh[0] = f2bf(p[tc][0]); u.sh[1] = f2bf(p[tc][1]);
            u.sh[2] = f2bf(p[tc][2]); u.sh[3] = f2bf(p[tc][3]);
            int wb = (lq * 128 + tc * 32 + g * 8) ^ swz;
            *(int2*)(myP + wb) = u.w;
        }
        asm volatile("s_waitcnt lgkmcnt(0)" ::: "memory");

        // ---- PV swapped: oacc[d] += mfma(V^T_frag, P_frag) ----
        #pragma unroll
        for (int kt = 0; kt < 2; ++kt) {
            int rb = (lq * 128 + kt * 64 + g * 16) ^ swz;
            bfrag pf = *(const bfrag*)(myP + rb);
            #pragma unroll
            for (int d = 0; d < 4; ++d) {
                bfrag vfr = *(const bfrag*)(&Vc[(d * 16 + lq) * 64 + (((kt * 4 + g) ^ l7) << 3)]);
                oacc[d] = __builtin_amdgcn_mfma_f32_16x16x32_bf16(vfr, pf, oacc[d], 0, 0, 0);
            }
        }
        __syncthreads();
    }

    // ---- epilogue ----
    const int b = bh >> 4, h = bh & 15;
    const float inv_l = 1.f / lrun;
    size_t rowbase = ((size_t)(b * S_LEN + qi)) * HDIM + h * DH;
    #pragma unroll
    for (int d = 0; d < 4; ++d) {
        union { short sh[4]; int2 w; } u;
        #pragma unroll
        for (int r = 0; r < 4; ++r)
            u.sh[r] = f2bf(oacc[d][r] * inv_l);
        *(int2*)(&attno[rowbase + d * 16 + 4 * g]) = u.w;
    }
}

extern "C" void kernel_launch(void* const* d_in, const int* in_sizes, int n_in,
                              void* d_out, int out_size, void* d_ws, size_t ws_size,
                              hipStream_t stream) {
    const float* x = (const float*)d_in[0];
    const float* Wqkv = (const float*)d_in[1];
    const float* Wout = (const float*)d_in[2];
    float* out = (float*)d_out;
    char* ws = (char*)d_ws;

    short* x_bf   = (short*)(ws);                    // 4096x1024        (8 MB)
    short* wqkv_t = (short*)(ws + 8388608);          // 3072x1024        (6 MB)
    short* wout_t = (short*)(ws + 14680064);         // 1024x1024        (2 MB)
    short* q_bf   = (short*)(ws + 16777216);         // [b][h][s][dh]    (8 MB)
    short* k_bf   = (short*)(ws + 25165824);         // [b][h][s][dh]    (8 MB)
    short* v_t    = (short*)(ws + 33554432);         // [b][h][dh][s]    (8 MB)
    short* attno  = (short*)(ws + 41943040);         // 4096x1024        (8 MB)

    cast_bf_kernel<<<4096, 256, 0, stream>>>(x, x_bf, MROWS * HDIM / 4);
    transpose_cast_kernel<<<dim3(96, 32), 256, 0, stream>>>(Wqkv, wqkv_t, 1024, 3072);
    transpose_cast_kernel<<<dim3(32, 32), 256, 0, stream>>>(Wout, wout_t, 1024, 1024);

    gemm_bt<<<dim3(24, 32), 256, 0, stream>>>(x_bf, wqkv_t, MROWS, 3 * HDIM, HDIM, 0,
                                              q_bf, k_bf, v_t, nullptr);
    attn_kernel<<<dim3(BATCH * NH * (S_LEN / 64)), 256, 0, stream>>>(q_bf, k_bf, v_t, attno);
    gemm_bt<<<dim3(8, 32), 256, 0, stream>>>(attno, wout_t, MROWS, HDIM, HDIM, 1,
                                             nullptr, nullptr, nullptr, out);
}

// Round 5
// 174.957 us; speedup vs baseline: 1.2383x; 1.0054x over previous
//
#include <hip/hip_runtime.h>

#define S_LEN 2048
#define BATCH 2
#define HDIM 1024
#define NH 16
#define DH 64
#define WINSZ 512
#define MROWS (BATCH * S_LEN)

typedef __attribute__((ext_vector_type(8))) short bfrag;
typedef __attribute__((ext_vector_type(4))) float f32x4;
typedef __attribute__((ext_vector_type(4))) int i128;

__device__ __forceinline__ short f2bf(float f) {
    union { float f; unsigned u; } v;
    v.f = f;
    unsigned r = v.u + 0x7fffu + ((v.u >> 16) & 1u);
    return (short)(r >> 16);
}

__device__ __forceinline__ void gload_lds16(const short* g, short* l) {
    __builtin_amdgcn_global_load_lds(
        (const __attribute__((address_space(1))) unsigned int*)g,
        (__attribute__((address_space(3))) unsigned int*)l, 16, 0, 0);
}

// ---------------- cast x (fp32 -> bf16), 4 elems/thread ----------------
__global__ void cast_bf_kernel(const float* __restrict__ in, short* __restrict__ out, int n4) {
    int i = blockIdx.x * blockDim.x + threadIdx.x;
    if (i < n4) {
        float4 v = ((const float4*)in)[i];
        union { short s[4]; int2 p; } u;
        u.s[0] = f2bf(v.x); u.s[1] = f2bf(v.y); u.s[2] = f2bf(v.z); u.s[3] = f2bf(v.w);
        ((int2*)out)[i] = u.p;
    }
}

// ---------------- transpose + cast: in (R x C fp32) -> out (C x R bf16) ----------------
__global__ void transpose_cast_kernel(const float* __restrict__ in, short* __restrict__ out,
                                      int R, int C) {
    __shared__ float tile[32][33];
    int tc0 = blockIdx.x * 32;
    int tr0 = blockIdx.y * 32;
    int t = threadIdx.x;
    int c = t & 31, r0 = t >> 5;
    #pragma unroll
    for (int k = 0; k < 4; ++k) {
        int r = r0 + k * 8;
        tile[r][c] = in[(size_t)(tr0 + r) * C + tc0 + c];
    }
    __syncthreads();
    int r2 = t & 31, c0 = t >> 5;
    #pragma unroll
    for (int k = 0; k < 4; ++k) {
        int c2 = c0 + k * 8;
        out[(size_t)(tc0 + c2) * R + tr0 + r2] = f2bf(tile[r2][c2]);
    }
}

// ---------------- GEMM: A (M x K bf16 rm) @ Bt (N x K bf16 rm), 2-phase prefetch ----------------
// mode 0: bf16 row-major store to cbf ; mode 1: fp32 row-major store to co
__global__ __launch_bounds__(256, 2)
void gemm_bt(const short* __restrict__ A, const short* __restrict__ Bt,
             int M, int N, int K, int mode,
             short* __restrict__ cbf, float* __restrict__ co)
{
    __shared__ __align__(16) short Al[2][128 * 32];
    __shared__ __align__(16) short Bl[2][128 * 32];
    const int t = threadIdx.x;
    const int lane = t & 63;
    const int wave = t >> 6;
    const int wr = wave >> 1, wc = wave & 1;
    const int m0 = blockIdx.y * 128, n0 = blockIdx.x * 128;
    const int lrow = lane & 15;
    const int lk8 = (lane >> 4) << 3;

    f32x4 acc[4][4];
    #pragma unroll
    for (int m = 0; m < 4; ++m)
        #pragma unroll
        for (int n = 0; n < 4; ++n)
            acc[m][n] = (f32x4){0.f, 0.f, 0.f, 0.f};

    const int row0s = t >> 2, col0s = (t & 3) << 3;
    const int row1s = (256 + t) >> 2, col1s = (t & 3) << 3;
    const size_t dst0 = (size_t)(wave * 64) * 8;
    const size_t dst1 = (size_t)(256 + wave * 64) * 8;

    auto stage = [&](int k0, int sb) {
        gload_lds16(&A[(size_t)(m0 + row0s) * K + k0 + col0s], &Al[sb][0] + dst0);
        gload_lds16(&Bt[(size_t)(n0 + row0s) * K + k0 + col0s], &Bl[sb][0] + dst0);
        gload_lds16(&A[(size_t)(m0 + row1s) * K + k0 + col1s], &Al[sb][0] + dst1);
        gload_lds16(&Bt[(size_t)(n0 + row1s) * K + k0 + col1s], &Bl[sb][0] + dst1);
    };

    const int nk = K >> 5;
    stage(0, 0);
    __syncthreads();
    for (int ki = 0; ki < nk; ++ki) {
        const int cur = ki & 1;
        if (ki + 1 < nk) stage((ki + 1) << 5, cur ^ 1);
        bfrag af[4], bfr[4];
        #pragma unroll
        for (int m = 0; m < 4; ++m)
            af[m] = *(const bfrag*)(&Al[cur][(wr * 64 + m * 16 + lrow) * 32 + lk8]);
        #pragma unroll
        for (int n = 0; n < 4; ++n)
            bfr[n] = *(const bfrag*)(&Bl[cur][(wc * 64 + n * 16 + lrow) * 32 + lk8]);
        #pragma unroll
        for (int m = 0; m < 4; ++m)
            #pragma unroll
            for (int n = 0; n < 4; ++n)
                acc[m][n] = __builtin_amdgcn_mfma_f32_16x16x32_bf16(af[m], bfr[n], acc[m][n], 0, 0, 0);
        __syncthreads();
    }

    if (mode == 1) {
        #pragma unroll
        for (int m = 0; m < 4; ++m)
            #pragma unroll
            for (int n = 0; n < 4; ++n) {
                int col = n0 + wc * 64 + n * 16 + lrow;
                int row0 = m0 + wr * 64 + m * 16 + ((lane >> 4) << 2);
                #pragma unroll
                for (int r = 0; r < 4; ++r)
                    co[(size_t)(row0 + r) * N + col] = acc[m][n][r];
            }
    } else {
        #pragma unroll
        for (int m = 0; m < 4; ++m)
            #pragma unroll
            for (int n = 0; n < 4; ++n) {
                int col = n0 + wc * 64 + n * 16 + lrow;
                int row0 = m0 + wr * 64 + m * 16 + ((lane >> 4) << 2);
                #pragma unroll
                for (int r = 0; r < 4; ++r)
                    cbf[(size_t)(row0 + r) * N + col] = f2bf(acc[m][n][r]);
            }
    }
}

// ---------------- V transpose: qkv_rm v-section [s][dh] -> v_t [b][h][dh][s] ----------------
__global__ __launch_bounds__(256)
void vtr_kernel(const short* __restrict__ qkv, short* __restrict__ vt) {
    __shared__ __align__(16) short tile[64][72];
    const int bh = blockIdx.x >> 5;          // 0..31
    const int s0 = (blockIdx.x & 31) << 6;   // 0..2047 step 64
    const int b = bh >> 4, h = bh & 15;
    const short* src = qkv + (size_t)b * S_LEN * 3072 + 2048 + h * 64;
    const int t = threadIdx.x;
    const int sl = t >> 2, dh0 = (t & 3) << 4;
    *(i128*)&tile[sl][dh0]     = *(const i128*)&src[(size_t)(s0 + sl) * 3072 + dh0];
    *(i128*)&tile[sl][dh0 + 8] = *(const i128*)&src[(size_t)(s0 + sl) * 3072 + dh0 + 8];
    __syncthreads();
    const int dhl = t >> 2, sc = (t & 3) << 4;
    union { short sh[8]; i128 v; } u0, u1;
    #pragma unroll
    for (int i = 0; i < 8; ++i) { u0.sh[i] = tile[sc + i][dhl]; u1.sh[i] = tile[sc + 8 + i][dhl]; }
    short* dst = vt + ((size_t)bh * DH + dhl) * S_LEN + s0 + sc;
    *(i128*)&dst[0] = u0.v;
    *(i128*)&dst[8] = u1.v;
}

// ---------------- sliding-window flash attention (block-shared LDS K/V tiles) ----------------
// Q/K read from qkv_rm (row stride 3072); V from v_t. Swapped-operand MFMA.
__global__ __launch_bounds__(256, 4)
void attn_kernel(const short* __restrict__ qkv, const short* __restrict__ vt,
                 short* __restrict__ attno)
{
    __shared__ __align__(16) short Kl[2][64 * 64];
    __shared__ __align__(16) short Vl[2][64 * 64];
    __shared__ __align__(16) short Pl[4][16 * 64];

    const int bid = blockIdx.x;
    const int logical = (bid & 7) * 128 + (bid >> 3);   // XCD-grouping (bijective: 1024%8==0)
    const int qblk = logical & 31;
    const int bh = logical >> 5;
    const int b = bh >> 4, h = bh & 15;

    const int t = threadIdx.x;
    const int wave = t >> 6, lane = t & 63;
    const int qb0 = qblk * 64;
    const int i0 = qb0 + wave * 16;
    const short* qbase = qkv + (size_t)b * S_LEN * 3072 + h * 64;          // q section
    const short* kbase = qkv + (size_t)b * S_LEN * 3072 + 1024 + h * 64;  // k section
    const short* vp = vt + (size_t)bh * DH * S_LEN;
    char* myP = (char*)&Pl[wave][0];

    const int lq = lane & 15;
    const int g = lane >> 4;
    const int swz = (lq & 7) << 4;
    const int l7 = lq & 7;

    bfrag qf[2];
    qf[0] = *(const bfrag*)(&qbase[(size_t)(i0 + lq) * 3072 + (g << 3)]);
    qf[1] = *(const bfrag*)(&qbase[(size_t)(i0 + lq) * 3072 + 32 + (g << 3)]);

    f32x4 oacc[4];
    #pragma unroll
    for (int d = 0; d < 4; ++d) oacc[d] = (f32x4){0.f, 0.f, 0.f, 0.f};
    float m2 = -1e30f, lrun = 0.f;
    const float QSCALE = 0.125f * 1.44269504f;
    const int qi = i0 + lq;

    int j_lo = qb0 - (WINSZ - 1);
    if (j_lo < 0) j_lo = 0;
    j_lo &= ~63;
    const int nT = ((qb0 + 64) - j_lo) >> 6;

    auto stage = [&](int j0, short* kbuf, short* vbuf) {
        #pragma unroll
        for (int qq = 0; qq < 2; ++qq) {
            int chunk = qq * 256 + wave * 64 + lane;
            int row = chunk >> 3;
            int cc = (chunk & 7) ^ (row & 7);
            short* kdst = kbuf + (size_t)(qq * 256 + wave * 64) * 8;
            short* vdst = vbuf + (size_t)(qq * 256 + wave * 64) * 8;
            gload_lds16(kbase + (size_t)(j_lo + j0 + row) * 3072 + cc * 8, kdst);
            gload_lds16(vp + (size_t)row * S_LEN + j_lo + j0 + cc * 8, vdst);
        }
    };

    stage(0, Kl[0], Vl[0]);
    __syncthreads();

    for (int ti = 0; ti < nT; ++ti) {
        const int cur = ti & 1;
        const int j0 = j_lo + ti * 64;
        if (ti + 1 < nT) stage((ti + 1) * 64, Kl[cur ^ 1], Vl[cur ^ 1]);

        const short* Kc = Kl[cur];
        const short* Vc = Vl[cur];

        f32x4 sc[4];
        #pragma unroll
        for (int tc = 0; tc < 4; ++tc) {
            bfrag a0 = *(const bfrag*)(&Kc[(tc * 16 + lq) * 64 + ((g ^ l7) << 3)]);
            bfrag a1 = *(const bfrag*)(&Kc[(tc * 16 + lq) * 64 + (((4 | g) ^ l7) << 3)]);
            f32x4 z = (f32x4){0.f, 0.f, 0.f, 0.f};
            z = __builtin_amdgcn_mfma_f32_16x16x32_bf16(a0, qf[0], z, 0, 0, 0);
            z = __builtin_amdgcn_mfma_f32_16x16x32_bf16(a1, qf[1], z, 0, 0, 0);
            sc[tc] = z;
        }

        const bool nomask = (j0 >= i0 - (WINSZ - 16)) && (j0 + 63 <= i0);
        float s[4][4];
        float pm = -1e30f;
        #pragma unroll
        for (int tc = 0; tc < 4; ++tc)
            #pragma unroll
            for (int r = 0; r < 4; ++r) {
                float sv = sc[tc][r] * QSCALE;
                if (!nomask) {
                    int kj = j0 + tc * 16 + 4 * g + r;
                    sv = ((kj <= qi) && (kj > qi - WINSZ)) ? sv : -1e30f;
                }
                s[tc][r] = sv;
                pm = fmaxf(pm, sv);
            }
        pm = fmaxf(pm, __shfl_xor(pm, 16));
        pm = fmaxf(pm, __shfl_xor(pm, 32));
        float mnew = fmaxf(m2, pm);
        float scale_old = exp2f(m2 - mnew);
        m2 = mnew;
        float p[4][4];
        float rs = 0.f;
        #pragma unroll
        for (int tc = 0; tc < 4; ++tc)
            #pragma unroll
            for (int r = 0; r < 4; ++r) {
                p[tc][r] = exp2f(s[tc][r] - mnew);
                rs += p[tc][r];
            }
        rs += __shfl_xor(rs, 16);
        rs += __shfl_xor(rs, 32);
        lrun = lrun * scale_old + rs;
        #pragma unroll
        for (int d = 0; d < 4; ++d) {
            f32x4 o = oacc[d];
            o[0] *= scale_old; o[1] *= scale_old; o[2] *= scale_old; o[3] *= scale_old;
            oacc[d] = o;
        }

        #pragma unroll
        for (int tc = 0; tc < 4; ++tc) {
            union { short sh[4]; int2 w; } u;
            u.sh[0] = f2bf(p[tc][0]); u.sh[1] = f2bf(p[tc][1]);
            u.sh[2] = f2bf(p[tc][2]); u.sh[3] = f2bf(p[tc][3]);
            int wb = (lq * 128 + tc * 32 + g * 8) ^ swz;
            *(int2*)(myP + wb) = u.w;
        }
        asm volatile("s_waitcnt lgkmcnt(0)" ::: "memory");

        #pragma unroll
        for (int kt = 0; kt < 2; ++kt) {
            int rb = (lq * 128 + kt * 64 + g * 16) ^ swz;
            bfrag pf = *(const bfrag*)(myP + rb);
            #pragma unroll
            for (int d = 0; d < 4; ++d) {
                bfrag vfr = *(const bfrag*)(&Vc[(d * 16 + lq) * 64 + (((kt * 4 + g) ^ l7) << 3)]);
                oacc[d] = __builtin_amdgcn_mfma_f32_16x16x32_bf16(vfr, pf, oacc[d], 0, 0, 0);
            }
        }
        __syncthreads();
    }

    const float inv_l = 1.f / lrun;
    size_t rowbase = ((size_t)(b * S_LEN + qi)) * HDIM + h * DH;
    #pragma unroll
    for (int d = 0; d < 4; ++d) {
        union { short sh[4]; int2 w; } u;
        #pragma unroll
        for (int r = 0; r < 4; ++r)
            u.sh[r] = f2bf(oacc[d][r] * inv_l);
        *(int2*)(&attno[rowbase + d * 16 + 4 * g]) = u.w;
    }
}

extern "C" void kernel_launch(void* const* d_in, const int* in_sizes, int n_in,
                              void* d_out, int out_size, void* d_ws, size_t ws_size,
                              hipStream_t stream) {
    const float* x = (const float*)d_in[0];
    const float* Wqkv = (const float*)d_in[1];
    const float* Wout = (const float*)d_in[2];
    float* out = (float*)d_out;
    char* ws = (char*)d_ws;

    short* x_bf   = (short*)(ws);                    // 4096x1024 bf16 (8 MB); later reused as attno
    short* wqkv_t = (short*)(ws + 8388608);          // 3072x1024      (6 MB)
    short* wout_t = (short*)(ws + 14680064);         // 1024x1024      (2 MB)
    short* qkv_rm = (short*)(ws + 16777216);         // 4096x3072 bf16 (24 MB)
    short* v_t    = (short*)(ws + 41943040);         // [b][h][dh][s]  (8 MB)
    short* attno  = x_bf;                            // alias: x_bf dead after QKV GEMM

    cast_bf_kernel<<<4096, 256, 0, stream>>>(x, x_bf, MROWS * HDIM / 4);
    transpose_cast_kernel<<<dim3(96, 32), 256, 0, stream>>>(Wqkv, wqkv_t, 1024, 3072);
    transpose_cast_kernel<<<dim3(32, 32), 256, 0, stream>>>(Wout, wout_t, 1024, 1024);

    gemm_bt<<<dim3(24, 32), 256, 0, stream>>>(x_bf, wqkv_t, MROWS, 3 * HDIM, HDIM, 0,
                                              qkv_rm, nullptr);
    vtr_kernel<<<1024, 256, 0, stream>>>(qkv_rm, v_t);
    attn_kernel<<<dim3(BATCH * NH * (S_LEN / 64)), 256, 0, stream>>>(qkv_rm, v_t, attno);
    gemm_bt<<<dim3(8, 32), 256, 0, stream>>>(attno, wout_t, MROWS, HDIM, HDIM, 1,
                                             nullptr, out);
}

// Round 6
// 166.596 us; speedup vs baseline: 1.3004x; 1.0502x over previous
//
#include <hip/hip_runtime.h>

#define S_LEN 2048
#define BATCH 2
#define HDIM 1024
#define NH 16
#define DH 64
#define WINSZ 512
#define MROWS (BATCH * S_LEN)

typedef __attribute__((ext_vector_type(8))) short bfrag;
typedef __attribute__((ext_vector_type(4))) float f32x4;
typedef __attribute__((ext_vector_type(4))) int i128;

__device__ __forceinline__ short f2bf(float f) {
    union { float f; unsigned u; } v;
    v.f = f;
    unsigned r = v.u + 0x7fffu + ((v.u >> 16) & 1u);
    return (short)(r >> 16);
}

__device__ __forceinline__ void gload_lds16(const short* g, short* l) {
    __builtin_amdgcn_global_load_lds(
        (const __attribute__((address_space(1))) unsigned int*)g,
        (__attribute__((address_space(3))) unsigned int*)l, 16, 0, 0);
}

// ---------------- fused prep: x cast (blocks 0..4095), Wqkv^T (4096..7167), Wout^T (7168..8191) ----
__global__ __launch_bounds__(256)
void prep_kernel(const float* __restrict__ x, const float* __restrict__ Wqkv,
                 const float* __restrict__ Wout,
                 short* __restrict__ x_bf, short* __restrict__ wqkv_t, short* __restrict__ wout_t)
{
    __shared__ float tile[32][33];
    const int bid = blockIdx.x;
    const int t = threadIdx.x;

    if (bid < 4096) {
        int i = bid * 256 + t;
        float4 v = ((const float4*)x)[i];
        union { short s[4]; int2 p; } u;
        u.s[0] = f2bf(v.x); u.s[1] = f2bf(v.y); u.s[2] = f2bf(v.z); u.s[3] = f2bf(v.w);
        ((int2*)x_bf)[i] = u.p;
        return;
    }

    const float* in;
    short* out;
    int R, C, bx, by;
    if (bid < 7168) {
        int lb = bid - 4096;
        in = Wqkv; out = wqkv_t; R = 1024; C = 3072;
        bx = lb % 96; by = lb / 96;
    } else {
        int lb = bid - 7168;
        in = Wout; out = wout_t; R = 1024; C = 1024;
        bx = lb & 31; by = lb >> 5;
    }
    int tc0 = bx * 32, tr0 = by * 32;
    int c = t & 31, r0 = t >> 5;
    #pragma unroll
    for (int k = 0; k < 4; ++k) {
        int r = r0 + k * 8;
        tile[r][c] = in[(size_t)(tr0 + r) * C + tc0 + c];
    }
    __syncthreads();
    int r2 = t & 31, c0 = t >> 5;
    #pragma unroll
    for (int k = 0; k < 4; ++k) {
        int c2 = c0 + k * 8;
        out[(size_t)(tc0 + c2) * R + tr0 + r2] = f2bf(tile[r2][c2]);
    }
}

// ---------------- QKV GEMM: x_bf (M x 1024) @ wqkv_t (3072 x 1024) ----------------
// q,k cols -> qk_rm [4096][2048] bf16; v cols -> LDS-transposed -> v_t [b][h][dh][s]
__global__ __launch_bounds__(256, 2)
void gemm_qkv(const short* __restrict__ A, const short* __restrict__ Bt,
              short* __restrict__ qk_rm, short* __restrict__ vto)
{
    __shared__ __align__(16) short smraw[17408];   // 34816 B: K-loop 32 KB dbuf; epilogue T[128][136]
    short (*Al)[4096] = (short(*)[4096])smraw;
    short (*Bl)[4096] = (short(*)[4096])(smraw + 8192);
    const int K = HDIM;
    const int t = threadIdx.x;
    const int lane = t & 63;
    const int wave = t >> 6;
    const int wr = wave >> 1, wc = wave & 1;
    const int m0 = blockIdx.y * 128, n0 = blockIdx.x * 128;
    const int lq = lane & 15;
    const int g = lane >> 4;
    const int lk8 = g << 3;

    f32x4 acc[4][4];
    #pragma unroll
    for (int m = 0; m < 4; ++m)
        #pragma unroll
        for (int n = 0; n < 4; ++n)
            acc[m][n] = (f32x4){0.f, 0.f, 0.f, 0.f};

    const int row0s = t >> 2, col0s = (t & 3) << 3;
    const int row1s = (256 + t) >> 2;
    const size_t dst0 = (size_t)(wave * 64) * 8;
    const size_t dst1 = (size_t)(256 + wave * 64) * 8;

    auto stage = [&](int k0, int sb) {
        gload_lds16(&A[(size_t)(m0 + row0s) * K + k0 + col0s], &Al[sb][0] + dst0);
        gload_lds16(&Bt[(size_t)(n0 + row0s) * K + k0 + col0s], &Bl[sb][0] + dst0);
        gload_lds16(&A[(size_t)(m0 + row1s) * K + k0 + col0s], &Al[sb][0] + dst1);
        gload_lds16(&Bt[(size_t)(n0 + row1s) * K + k0 + col0s], &Bl[sb][0] + dst1);
    };

    const int nk = K >> 5;
    stage(0, 0);
    __syncthreads();
    for (int ki = 0; ki < nk; ++ki) {
        const int cur = ki & 1;
        if (ki + 1 < nk) stage((ki + 1) << 5, cur ^ 1);
        bfrag af[4], bfr[4];
        #pragma unroll
        for (int m = 0; m < 4; ++m)
            af[m] = *(const bfrag*)(&Al[cur][(wr * 64 + m * 16 + lq) * 32 + lk8]);
        #pragma unroll
        for (int n = 0; n < 4; ++n)
            bfr[n] = *(const bfrag*)(&Bl[cur][(wc * 64 + n * 16 + lq) * 32 + lk8]);
        #pragma unroll
        for (int m = 0; m < 4; ++m)
            #pragma unroll
            for (int n = 0; n < 4; ++n)
                acc[m][n] = __builtin_amdgcn_mfma_f32_16x16x32_bf16(af[m], bfr[n], acc[m][n], 0, 0, 0);
        __syncthreads();
    }

    if (n0 < 2048) {
        // q/k columns: plain row-major store
        #pragma unroll
        for (int m = 0; m < 4; ++m)
            #pragma unroll
            for (int n = 0; n < 4; ++n) {
                int col = n0 + wc * 64 + n * 16 + lq;
                int row0 = m0 + wr * 64 + m * 16 + g * 4;
                #pragma unroll
                for (int r = 0; r < 4; ++r)
                    qk_rm[(size_t)(row0 + r) * 2048 + col] = f2bf(acc[m][n][r]);
            }
    } else {
        // v columns: transpose 128x128 tile via LDS, write v_t [bh][dh][s]
        short* T = smraw;   // [128][136]
        #pragma unroll
        for (int m = 0; m < 4; ++m)
            #pragma unroll
            for (int n = 0; n < 4; ++n) {
                int cl = wc * 64 + n * 16 + lq;
                int rl0 = wr * 64 + m * 16 + g * 4;
                union { short sh[4]; int2 w; } u;
                #pragma unroll
                for (int r = 0; r < 4; ++r) u.sh[r] = f2bf(acc[m][n][r]);
                *(int2*)(&T[cl * 136 + rl0]) = u.w;
            }
        __syncthreads();
        const int b = m0 >> 11, sbase = m0 & 2047;
        const int h0 = (n0 - 2048) >> 6;
        #pragma unroll
        for (int i = 0; i < 8; ++i) {
            int c2 = i * 256 + t;          // 0..2047
            int rv = c2 >> 4;              // col-local 0..127 -> (h,dh)
            int sc = (c2 & 15) << 3;       // s-offset 0..120
            int h = h0 + (rv >> 6), dh = rv & 63;
            i128 v = *(const i128*)(&T[rv * 136 + sc]);
            *(i128*)(&vto[((size_t)((b * NH + h) * DH + dh)) * S_LEN + sbase + sc]) = v;
        }
    }
}

// ---------------- out GEMM: attno (M x 1024) @ wout_t (1024 x 1024) -> fp32 out ----------------
__global__ __launch_bounds__(256, 2)
void gemm_out(const short* __restrict__ A, const short* __restrict__ Bt,
              float* __restrict__ co)
{
    __shared__ __align__(16) short Al[2][128 * 32];
    __shared__ __align__(16) short Bl[2][128 * 32];
    const int K = HDIM, N = HDIM;
    const int t = threadIdx.x;
    const int lane = t & 63;
    const int wave = t >> 6;
    const int wr = wave >> 1, wc = wave & 1;
    const int m0 = blockIdx.y * 128, n0 = blockIdx.x * 128;
    const int lq = lane & 15;
    const int g = lane >> 4;
    const int lk8 = g << 3;

    f32x4 acc[4][4];
    #pragma unroll
    for (int m = 0; m < 4; ++m)
        #pragma unroll
        for (int n = 0; n < 4; ++n)
            acc[m][n] = (f32x4){0.f, 0.f, 0.f, 0.f};

    const int row0s = t >> 2, col0s = (t & 3) << 3;
    const int row1s = (256 + t) >> 2;
    const size_t dst0 = (size_t)(wave * 64) * 8;
    const size_t dst1 = (size_t)(256 + wave * 64) * 8;

    auto stage = [&](int k0, int sb) {
        gload_lds16(&A[(size_t)(m0 + row0s) * K + k0 + col0s], &Al[sb][0] + dst0);
        gload_lds16(&Bt[(size_t)(n0 + row0s) * K + k0 + col0s], &Bl[sb][0] + dst0);
        gload_lds16(&A[(size_t)(m0 + row1s) * K + k0 + col0s], &Al[sb][0] + dst1);
        gload_lds16(&Bt[(size_t)(n0 + row1s) * K + k0 + col0s], &Bl[sb][0] + dst1);
    };

    const int nk = K >> 5;
    stage(0, 0);
    __syncthreads();
    for (int ki = 0; ki < nk; ++ki) {
        const int cur = ki & 1;
        if (ki + 1 < nk) stage((ki + 1) << 5, cur ^ 1);
        bfrag af[4], bfr[4];
        #pragma unroll
        for (int m = 0; m < 4; ++m)
            af[m] = *(const bfrag*)(&Al[cur][(wr * 64 + m * 16 + lq) * 32 + lk8]);
        #pragma unroll
        for (int n = 0; n < 4; ++n)
            bfr[n] = *(const bfrag*)(&Bl[cur][(wc * 64 + n * 16 + lq) * 32 + lk8]);
        #pragma unroll
        for (int m = 0; m < 4; ++m)
            #pragma unroll
            for (int n = 0; n < 4; ++n)
                acc[m][n] = __builtin_amdgcn_mfma_f32_16x16x32_bf16(af[m], bfr[n], acc[m][n], 0, 0, 0);
        __syncthreads();
    }

    #pragma unroll
    for (int m = 0; m < 4; ++m)
        #pragma unroll
        for (int n = 0; n < 4; ++n) {
            int col = n0 + wc * 64 + n * 16 + lq;
            int row0 = m0 + wr * 64 + m * 16 + g * 4;
            #pragma unroll
            for (int r = 0; r < 4; ++r)
                co[(size_t)(row0 + r) * N + col] = acc[m][n][r];
        }
}

// ---------------- sliding-window flash attention ----------------
__global__ __launch_bounds__(256, 4)
void attn_kernel(const short* __restrict__ qk, const short* __restrict__ vt,
                 short* __restrict__ attno)
{
    __shared__ __align__(16) short Kl[2][64 * 64];
    __shared__ __align__(16) short Vl[2][64 * 64];
    __shared__ __align__(16) short Pl[4][16 * 64];

    const int bid = blockIdx.x;
    const int logical = (bid & 7) * 128 + (bid >> 3);   // XCD-grouping (bijective: 1024%8==0)
    const int qblk = logical & 31;
    const int bh = logical >> 5;
    const int b = bh >> 4, h = bh & 15;

    const int t = threadIdx.x;
    const int wave = t >> 6, lane = t & 63;
    const int qb0 = qblk * 64;
    const int i0 = qb0 + wave * 16;
    const short* qbase = qk + (size_t)b * S_LEN * 2048 + h * 64;
    const short* kbase = qk + (size_t)b * S_LEN * 2048 + 1024 + h * 64;
    const short* vp = vt + (size_t)bh * DH * S_LEN;
    char* myP = (char*)&Pl[wave][0];

    const int lq = lane & 15;
    const int g = lane >> 4;
    const int swz = (lq & 7) << 4;
    const int l7 = lq & 7;

    bfrag qf[2];
    qf[0] = *(const bfrag*)(&qbase[(size_t)(i0 + lq) * 2048 + (g << 3)]);
    qf[1] = *(const bfrag*)(&qbase[(size_t)(i0 + lq) * 2048 + 32 + (g << 3)]);

    f32x4 oacc[4];
    #pragma unroll
    for (int d = 0; d < 4; ++d) oacc[d] = (f32x4){0.f, 0.f, 0.f, 0.f};
    float m2 = -1e30f, lrun = 0.f;
    const float QSCALE = 0.125f * 1.44269504f;
    const int qi = i0 + lq;

    int j_lo = qb0 - (WINSZ - 1);
    if (j_lo < 0) j_lo = 0;
    j_lo &= ~63;
    const int nT = ((qb0 + 64) - j_lo) >> 6;

    auto stage = [&](int j0, short* kbuf, short* vbuf) {
        #pragma unroll
        for (int qq = 0; qq < 2; ++qq) {
            int chunk = qq * 256 + wave * 64 + lane;
            int row = chunk >> 3;
            int cc = (chunk & 7) ^ (row & 7);
            short* kdst = kbuf + (size_t)(qq * 256 + wave * 64) * 8;
            short* vdst = vbuf + (size_t)(qq * 256 + wave * 64) * 8;
            gload_lds16(kbase + (size_t)(j_lo + j0 + row) * 2048 + cc * 8, kdst);
            gload_lds16(vp + (size_t)row * S_LEN + j_lo + j0 + cc * 8, vdst);
        }
    };

    stage(0, Kl[0], Vl[0]);
    __syncthreads();

    for (int ti = 0; ti < nT; ++ti) {
        const int cur = ti & 1;
        const int j0 = j_lo + ti * 64;
        if (ti + 1 < nT) stage((ti + 1) * 64, Kl[cur ^ 1], Vl[cur ^ 1]);

        const short* Kc = Kl[cur];
        const short* Vc = Vl[cur];

        f32x4 sc[4];
        __builtin_amdgcn_s_setprio(1);
        #pragma unroll
        for (int tc = 0; tc < 4; ++tc) {
            bfrag a0 = *(const bfrag*)(&Kc[(tc * 16 + lq) * 64 + ((g ^ l7) << 3)]);
            bfrag a1 = *(const bfrag*)(&Kc[(tc * 16 + lq) * 64 + (((4 | g) ^ l7) << 3)]);
            f32x4 z = (f32x4){0.f, 0.f, 0.f, 0.f};
            z = __builtin_amdgcn_mfma_f32_16x16x32_bf16(a0, qf[0], z, 0, 0, 0);
            z = __builtin_amdgcn_mfma_f32_16x16x32_bf16(a1, qf[1], z, 0, 0, 0);
            sc[tc] = z;
        }
        __builtin_amdgcn_s_setprio(0);

        const bool nomask = (j0 >= i0 - (WINSZ - 16)) && (j0 + 63 <= i0);
        float s[4][4];
        float pm = -1e30f;
        #pragma unroll
        for (int tc = 0; tc < 4; ++tc)
            #pragma unroll
            for (int r = 0; r < 4; ++r) {
                float sv = sc[tc][r] * QSCALE;
                if (!nomask) {
                    int kj = j0 + tc * 16 + 4 * g + r;
                    sv = ((kj <= qi) && (kj > qi - WINSZ)) ? sv : -1e30f;
                }
                s[tc][r] = sv;
                pm = fmaxf(pm, sv);
            }
        pm = fmaxf(pm, __shfl_xor(pm, 16));
        pm = fmaxf(pm, __shfl_xor(pm, 32));
        float mnew = fmaxf(m2, pm);
        float scale_old = exp2f(m2 - mnew);
        m2 = mnew;
        float p[4][4];
        float rs = 0.f;
        #pragma unroll
        for (int tc = 0; tc < 4; ++tc)
            #pragma unroll
            for (int r = 0; r < 4; ++r) {
                p[tc][r] = exp2f(s[tc][r] - mnew);
                rs += p[tc][r];
            }
        rs += __shfl_xor(rs, 16);
        rs += __shfl_xor(rs, 32);
        lrun = lrun * scale_old + rs;
        #pragma unroll
        for (int d = 0; d < 4; ++d) {
            f32x4 o = oacc[d];
            o[0] *= scale_old; o[1] *= scale_old; o[2] *= scale_old; o[3] *= scale_old;
            oacc[d] = o;
        }

        #pragma unroll
        for (int tc = 0; tc < 4; ++tc) {
            union { short sh[4]; int2 w; } u;
            u.sh[0] = f2bf(p[tc][0]); u.sh[1] = f2bf(p[tc][1]);
            u.sh[2] = f2bf(p[tc][2]); u.sh[3] = f2bf(p[tc][3]);
            int wb = (lq * 128 + tc * 32 + g * 8) ^ swz;
            *(int2*)(myP + wb) = u.w;
        }
        asm volatile("s_waitcnt lgkmcnt(0)" ::: "memory");

        __builtin_amdgcn_s_setprio(1);
        #pragma unroll
        for (int kt = 0; kt < 2; ++kt) {
            int rb = (lq * 128 + kt * 64 + g * 16) ^ swz;
            bfrag pf = *(const bfrag*)(myP + rb);
            #pragma unroll
            for (int d = 0; d < 4; ++d) {
                bfrag vfr = *(const bfrag*)(&Vc[(d * 16 + lq) * 64 + (((kt * 4 + g) ^ l7) << 3)]);
                oacc[d] = __builtin_amdgcn_mfma_f32_16x16x32_bf16(vfr, pf, oacc[d], 0, 0, 0);
            }
        }
        __builtin_amdgcn_s_setprio(0);
        __syncthreads();
    }

    const float inv_l = 1.f / lrun;
    size_t rowbase = ((size_t)(b * S_LEN + qi)) * HDIM + h * DH;
    #pragma unroll
    for (int d = 0; d < 4; ++d) {
        union { short sh[4]; int2 w; } u;
        #pragma unroll
        for (int r = 0; r < 4; ++r)
            u.sh[r] = f2bf(oacc[d][r] * inv_l);
        *(int2*)(&attno[rowbase + d * 16 + 4 * g]) = u.w;
    }
}

extern "C" void kernel_launch(void* const* d_in, const int* in_sizes, int n_in,
                              void* d_out, int out_size, void* d_ws, size_t ws_size,
                              hipStream_t stream) {
    const float* x = (const float*)d_in[0];
    const float* Wqkv = (const float*)d_in[1];
    const float* Wout = (const float*)d_in[2];
    float* out = (float*)d_out;
    char* ws = (char*)d_ws;

    short* x_bf   = (short*)(ws);                    // 4096x1024 bf16 (8 MB); reused as attno
    short* wqkv_t = (short*)(ws + 8388608);          // 3072x1024      (6 MB)
    short* wout_t = (short*)(ws + 14680064);         // 1024x1024      (2 MB)
    short* qk_rm  = (short*)(ws + 16777216);         // 4096x2048 bf16 (16 MB)
    short* v_t    = (short*)(ws + 33554432);         // [b][h][dh][s]  (8 MB)
    short* attno  = x_bf;                            // alias: x_bf dead after QKV GEMM

    prep_kernel<<<8192, 256, 0, stream>>>(x, Wqkv, Wout, x_bf, wqkv_t, wout_t);
    gemm_qkv<<<dim3(24, 32), 256, 0, stream>>>(x_bf, wqkv_t, qk_rm, v_t);
    attn_kernel<<<dim3(BATCH * NH * (S_LEN / 64)), 256, 0, stream>>>(qk_rm, v_t, attno);
    gemm_out<<<dim3(8, 32), 256, 0, stream>>>(attno, wout_t, out);
}